// Round 11
// baseline (446.548 us; speedup 1.0000x reference)
//
#include <hip/hip_runtime.h>
#include <hip/hip_fp16.h>

constexpr int BLK = 256;

static inline int cdiv(long long a, int b) { return (int)((a + b - 1) / b); }

using v8h = __attribute__((ext_vector_type(8))) _Float16;
using v4f = __attribute__((ext_vector_type(4))) float;

// ---------------- layout / scheduling notes (R7-R10 post-mortems) ----------
// hbuf (GEMM->agg shadow): SUPERPLANE-32 = 3 planes x [N][32]; (n,c) at
//   [(c>>5)*N + n]*32 + (c&31). XCD-affine plane-major agg blocks -> gather
//   working set ~3.2MB/XCD, L2-resident (R8: FETCH 89.6->14.6MB).
// buf2h / proj1 out: ROW-MAJOR [N][96] fp16 (streaming consumers, R9 lesson).
// R10 lessons: agg is latency/issue bound (~43us) NOT fetch-bound; waves
//   stall on max-degree node of the 16 they serve -> DEGREE-SORTED perm this
//   round. gemm1+count merge throttled count via 26KB LDS (occ 36%) -> split.
// R4: grid.sync ~60us — never. R5: no spin-waits. R6: launch overhead ~2us.

// ---------------- degree / CSR build ----------------

// count in-degree; record per-edge within-node offset as uint16 (deg < 64K)
__global__ void count_dst_off(const int* __restrict__ dst, int* __restrict__ cnt,
                              unsigned short* __restrict__ eoff, int E) {
    for (int i = blockIdx.x * blockDim.x + threadIdx.x; i < E; i += gridDim.x * blockDim.x)
        eoff[i] = (unsigned short)atomicAdd(&cnt[dst[i]], 1);
}

// block scans 1024 elements (256 threads x 4); emits dis = rsqrt(cnt+1);
// also accumulates a 64-bucket degree histogram (clamped) into ghist.
__global__ __launch_bounds__(256) void scan1_dis(const int* __restrict__ cnt,
                                                 int* __restrict__ rowptr,
                                                 int* __restrict__ bsum,
                                                 float* __restrict__ dis,
                                                 int* __restrict__ ghist, int N) {
    __shared__ int ts[256];
    __shared__ int lh[64];
    int tid = threadIdx.x;
    if (tid < 64) lh[tid] = 0;
    int base = blockIdx.x * 1024 + tid * 4;
    int v[4], s = 0;
#pragma unroll
    for (int i = 0; i < 4; ++i) {
        v[i] = (base + i < N) ? cnt[base + i] : 0;
        s += v[i];
        if (base + i < N) dis[base + i] = rsqrtf((float)v[i] + 1.0f);
    }
    ts[tid] = s;
    __syncthreads();  // lh zeroing + ts visible
#pragma unroll
    for (int i = 0; i < 4; ++i) {
        if (base + i < N) atomicAdd(&lh[v[i] < 63 ? v[i] : 63], 1);
    }
    for (int off = 1; off < 256; off <<= 1) {
        int t = 0;
        if (tid >= off) t = ts[tid - off];
        __syncthreads();
        if (tid >= off) ts[tid] += t;
        __syncthreads();
    }
    int run = ts[tid] - s;
#pragma unroll
    for (int i = 0; i < 4; ++i) {
        if (base + i < N) rowptr[base + i] = run;
        run += v[i];
    }
    if (tid == 255) bsum[blockIdx.x] = ts[255];
    __syncthreads();  // all lh atomics complete
    if (tid < 64) {
        int c = lh[tid];
        if (c) atomicAdd(&ghist[tid], c);
    }
}

// merged scan2+scan3 + degree-sort scatter:
// wave 0 scans the <=64 chunk sums; wave 1 scans the 64-bucket histogram.
// Then each node applies its chunk offset AND claims its degree-sorted slot
// (slot = bucket base + atomic ticket) -> perm groups similar-degree nodes
// so agg waves run balanced edge loops.
__global__ __launch_bounds__(256) void scan23(int* __restrict__ rowptr,
                                              const int* __restrict__ bsum,
                                              const int* __restrict__ cnt,
                                              const int* __restrict__ ghist,
                                              int* __restrict__ gcur,
                                              unsigned short* __restrict__ perm,
                                              int nb, int N, int E) {
    __shared__ int sboff[64];
    __shared__ int gb[64];
    const int tid = threadIdx.x;
    if (tid < 64) {
        int orig = (tid < nb) ? bsum[tid] : 0;
        int v = orig;
#pragma unroll
        for (int off = 1; off < 64; off <<= 1) {
            int t = __shfl_up(v, off, 64);
            if (tid >= off) v += t;
        }
        sboff[tid] = v - orig;  // exclusive prefix of chunk sums
    } else if (tid < 128) {
        int b = tid - 64;       // lane b of wave 1
        int h = ghist[b];
        int v = h;
#pragma unroll
        for (int off = 1; off < 64; off <<= 1) {
            int t = __shfl_up(v, off, 64);
            if (b >= off) v += t;
        }
        gb[b] = v - h;          // exclusive prefix of degree buckets
    }
    __syncthreads();
    int i = blockIdx.x * 256 + tid;
    if (i < N) {
        rowptr[i] += sboff[i >> 10];
        int d = cnt[i];
        d = d < 63 ? d : 63;
        int slot = gb[d] + atomicAdd(&gcur[d], 1);
        perm[slot] = (unsigned short)i;
    }
    if (i == 0) rowptr[N] = E;
}

// atomic-free scatter of 2-B src index: slot = rowptr[dst] + eoff (bijection)
__global__ void csr_fill(const int* __restrict__ src, const int* __restrict__ dst,
                         const unsigned short* __restrict__ eoff,
                         const int* __restrict__ rowptr,
                         unsigned short* __restrict__ csrc, int E) {
    for (int i = blockIdx.x * blockDim.x + threadIdx.x; i < E; i += gridDim.x * blockDim.x) {
        csrc[rowptr[dst[i]] + (int)eoff[i]] = (unsigned short)src[i];
    }
}

// ---------------- MFMA GEMM body: act(in)[N,K] @ W[K,96] (+bias) ------------
// TIN=float: row-major fp32 input (layer 1). TIN=_Float16: ROW-MAJOR fp16.
// OUTSP=true: fp16 SUPERPLANE-32 output (feeds agg). false: row-major fp16.
// Optional pre-scale by dsc[row]. STATS: column sum/sumsq (fp32) into osums.

template <int K, bool ACT, bool BIAS, bool STATS, bool OUTSP, typename TIN>
__device__ __forceinline__ void gemm96_body(int bid,
                                            const TIN* __restrict__ in,
                                            const float* __restrict__ W,
                                            const float* __restrict__ bias,
                                            const float* __restrict__ bnsums,
                                            const float* __restrict__ gamma,
                                            const float* __restrict__ beta,
                                            const float* __restrict__ dsc,
                                            _Float16* __restrict__ hout,
                                            float* __restrict__ osums, int N) {
    constexpr int NK = K / 32;
    constexpr int LDK = K + 8;
    __shared__ __align__(16) _Float16 Wt[96 * LDK];
    __shared__ __align__(16) float ssl[ACT ? 192 : 1];
    __shared__ float sb[STATS ? 192 : 1];
    const int tid = threadIdx.x;
    for (int idx = tid; idx < K * 96; idx += 256) {
        int k = idx / 96, n = idx - k * 96;
        Wt[n * LDK + k] = (_Float16)W[idx];
    }
    if (ACT && tid < 96) {
        float inv_n = 1.0f / (float)N;
        float mean = bnsums[tid] * inv_n;
        float var = bnsums[96 + tid] * inv_n - mean * mean;
        float sc = gamma[tid] * rsqrtf(var + 1e-5f);
        ssl[tid] = sc;
        ssl[96 + tid] = beta[tid] - mean * sc;
    }
    if (STATS && tid < 192) sb[tid] = 0.0f;
    __syncthreads();

    const int wave = tid >> 6, lane = tid & 63;
    const int quad = lane >> 4, lm = lane & 15;
    const int rbase = bid * 64 + wave * 16;
    int arow = rbase + lm;
    arow = arow < N ? arow : N - 1;

    v8h afr[NK];
#pragma unroll
    for (int kc = 0; kc < NK; ++kc) {
        const int kk = kc * 32 + quad * 8;
        if constexpr (sizeof(TIN) == 4) {
            const float* p = (const float*)&in[(long long)arow * K + kk];
            float4 p0 = *(const float4*)p;
            float4 p1 = *(const float4*)(p + 4);
            if (ACT) {
                float4 sc0 = *(const float4*)&ssl[kk];
                float4 sc1 = *(const float4*)&ssl[kk + 4];
                float4 sh0 = *(const float4*)&ssl[96 + kk];
                float4 sh1 = *(const float4*)&ssl[96 + kk + 4];
                p0.x = fmaxf(fmaf(p0.x, sc0.x, sh0.x), 0.0f);
                p0.y = fmaxf(fmaf(p0.y, sc0.y, sh0.y), 0.0f);
                p0.z = fmaxf(fmaf(p0.z, sc0.z, sh0.z), 0.0f);
                p0.w = fmaxf(fmaf(p0.w, sc0.w, sh0.w), 0.0f);
                p1.x = fmaxf(fmaf(p1.x, sc1.x, sh1.x), 0.0f);
                p1.y = fmaxf(fmaf(p1.y, sc1.y, sh1.y), 0.0f);
                p1.z = fmaxf(fmaf(p1.z, sc1.z, sh1.z), 0.0f);
                p1.w = fmaxf(fmaf(p1.w, sc1.w, sh1.w), 0.0f);
            }
            v8h a;
            a[0] = (_Float16)p0.x; a[1] = (_Float16)p0.y;
            a[2] = (_Float16)p0.z; a[3] = (_Float16)p0.w;
            a[4] = (_Float16)p1.x; a[5] = (_Float16)p1.y;
            a[6] = (_Float16)p1.z; a[7] = (_Float16)p1.w;
            afr[kc] = a;
        } else {
            // row-major fp16 read: 16-B contiguous per lane, 192-B rows (R7)
            v8h hv = *(const v8h*)&in[(long long)arow * 96 + kk];
            if (ACT) {
#pragma unroll
                for (int j = 0; j < 8; ++j) {
                    float f = (float)hv[j];
                    f = fmaxf(fmaf(f, ssl[kk + j], ssl[96 + kk + j]), 0.0f);
                    hv[j] = (_Float16)f;
                }
            }
            afr[kc] = hv;
        }
    }

    v4f acc[6];
#pragma unroll
    for (int t = 0; t < 6; ++t) {
        v4f c = {0.0f, 0.0f, 0.0f, 0.0f};
#pragma unroll
        for (int kc = 0; kc < NK; ++kc) {
            v8h b = *(const v8h*)&Wt[(t * 16 + lm) * LDK + kc * 32 + quad * 8];
            c = __builtin_amdgcn_mfma_f32_16x16x32_f16(afr[kc], b, c, 0, 0, 0);
        }
        acc[t] = c;
    }

    float dr[4];
#pragma unroll
    for (int r = 0; r < 4; ++r) {
        int gr = rbase + quad * 4 + r;
        dr[r] = dsc ? dsc[gr < N ? gr : N - 1] : 1.0f;
    }

    float ls[6], lq[6];
#pragma unroll
    for (int t = 0; t < 6; ++t) { ls[t] = 0.0f; lq[t] = 0.0f; }
#pragma unroll
    for (int t = 0; t < 6; ++t) {
        float bv = BIAS ? bias[t * 16 + lm] : 0.0f;
#pragma unroll
        for (int r = 0; r < 4; ++r) {
            int gr = rbase + quad * 4 + r;
            if (gr < N) {
                float o = acc[t][r] + bv;
                if (OUTSP) {
                    // superplane: plane = t>>1, within-plane col = (t&1)*16+lm
                    hout[(((long long)(t >> 1) * N + gr) * 32) + (t & 1) * 16 + lm] =
                        (_Float16)(o * dr[r]);
                } else {
                    hout[(long long)gr * 96 + t * 16 + lm] = (_Float16)(o * dr[r]);
                }
                if (STATS) { ls[t] += o; lq[t] += o * o; }
            }
        }
    }
    if (STATS) {
#pragma unroll
        for (int t = 0; t < 6; ++t) {
            ls[t] += __shfl_xor(ls[t], 16);
            ls[t] += __shfl_xor(ls[t], 32);
            lq[t] += __shfl_xor(lq[t], 16);
            lq[t] += __shfl_xor(lq[t], 32);
        }
        if (quad == 0) {
#pragma unroll
            for (int t = 0; t < 6; ++t) {
                atomicAdd(&sb[t * 16 + lm], ls[t]);
                atomicAdd(&sb[96 + t * 16 + lm], lq[t]);
            }
        }
        __syncthreads();
        if (tid < 192) atomicAdd(&osums[tid], sb[tid]);
    }
}

template <int K, bool ACT, bool BIAS, bool STATS, bool OUTSP, typename TIN>
__global__ __launch_bounds__(256) void gemm96m(const TIN* __restrict__ in,
                                               const float* __restrict__ W,
                                               const float* __restrict__ bias,
                                               const float* __restrict__ bnsums,
                                               const float* __restrict__ gamma,
                                               const float* __restrict__ beta,
                                               const float* __restrict__ dsc,
                                               _Float16* __restrict__ hout,
                                               float* __restrict__ osums, int N) {
    gemm96_body<K, ACT, BIAS, STATS, OUTSP, TIN>(blockIdx.x, in, W, bias, bnsums,
                                                 gamma, beta, dsc, hout, osums, N);
}

// ---------------- MFMA final GEMM: l2norm(act(in) @ Wp2[96,64] + bp2) -------
// in: ROW-MAJOR fp16 (R7-proven form).

__global__ __launch_bounds__(256) void gemm_finalm(const _Float16* __restrict__ in,
                                                   const float* __restrict__ W,
                                                   const float* __restrict__ bias,
                                                   const float* __restrict__ bnsums,
                                                   const float* __restrict__ gamma,
                                                   const float* __restrict__ beta,
                                                   float* __restrict__ out, int N) {
    constexpr int K = 96, NK = 3, LDK = K + 8;
    __shared__ __align__(16) _Float16 Wt[64 * LDK];
    __shared__ __align__(16) float ssl[192];
    const int tid = threadIdx.x;
    for (int idx = tid; idx < K * 64; idx += 256) {
        int k = idx / 64, n = idx - k * 64;
        Wt[n * LDK + k] = (_Float16)W[idx];
    }
    if (tid < 96) {
        float inv_n = 1.0f / (float)N;
        float mean = bnsums[tid] * inv_n;
        float var = bnsums[96 + tid] * inv_n - mean * mean;
        float sc = gamma[tid] * rsqrtf(var + 1e-5f);
        ssl[tid] = sc;
        ssl[96 + tid] = beta[tid] - mean * sc;
    }
    __syncthreads();

    const int wave = tid >> 6, lane = tid & 63;
    const int quad = lane >> 4, lm = lane & 15;
    const int rbase = blockIdx.x * 64 + wave * 16;
    int arow = rbase + lm;
    arow = arow < N ? arow : N - 1;

    v8h afr[NK];
#pragma unroll
    for (int kc = 0; kc < NK; ++kc) {
        const int kk = kc * 32 + quad * 8;
        v8h hv = *(const v8h*)&in[(long long)arow * 96 + kk];
#pragma unroll
        for (int j = 0; j < 8; ++j) {
            float f = (float)hv[j];
            f = fmaxf(fmaf(f, ssl[kk + j], ssl[96 + kk + j]), 0.0f);
            hv[j] = (_Float16)f;
        }
        afr[kc] = hv;
    }

    v4f acc[4];
#pragma unroll
    for (int t = 0; t < 4; ++t) {
        v4f c = {0.0f, 0.0f, 0.0f, 0.0f};
#pragma unroll
        for (int kc = 0; kc < NK; ++kc) {
            v8h b = *(const v8h*)&Wt[(t * 16 + lm) * LDK + kc * 32 + quad * 8];
            c = __builtin_amdgcn_mfma_f32_16x16x32_f16(afr[kc], b, c, 0, 0, 0);
        }
        float bv = bias[t * 16 + lm];
        c[0] += bv; c[1] += bv; c[2] += bv; c[3] += bv;
        acc[t] = c;
    }

    float sq[4];
#pragma unroll
    for (int r = 0; r < 4; ++r) {
        float s = acc[0][r] * acc[0][r] + acc[1][r] * acc[1][r] +
                  acc[2][r] * acc[2][r] + acc[3][r] * acc[3][r];
#pragma unroll
        for (int m = 1; m < 16; m <<= 1) s += __shfl_xor(s, m, 64);
        sq[r] = 1.0f / fmaxf(sqrtf(s), 1e-12f);
    }
#pragma unroll
    for (int r = 0; r < 4; ++r) {
        int gr = rbase + quad * 4 + r;
        if (gr < N) {
#pragma unroll
            for (int t = 0; t < 4; ++t)
                out[(long long)gr * 64 + t * 16 + lm] = acc[t][r] * sq[r];
        }
    }
}

// ---------------- CSR pull aggregation: superplane in, row-major out ---------
// Block = 64 perm-slots x 4 col-threads for one plane (4 lanes of a node read
// one contiguous 64-B line per edge). Plane-major wid + %8 bijective swizzle
// -> XCD-local 3.2MB plane (L2-resident, R8). Nodes taken via degree-sorted
// perm so the 16 nodes of a wave have similar degree -> balanced edge loops.
// PRESC=true : rows pre-scaled by dis[src] -> out = b + dn*(h[n] + sum h[s])
// PRESC=false: acc = dn*h[n] + sum dis[s]*h[s]; out = b + dn*acc

template <bool PRESC>
__global__ __launch_bounds__(256) void agg32p(const __half* __restrict__ hxw,
                                              const int* __restrict__ rowptr,
                                              const unsigned short* __restrict__ csrc,
                                              const float* __restrict__ dis,
                                              const float* __restrict__ bias,
                                              const unsigned short* __restrict__ perm,
                                              _Float16* __restrict__ outh,
                                              int nchp, int N) {
    int nwg = gridDim.x;  // 3*nchp, divisible by 8
    int wid = (blockIdx.x & 7) * (nwg >> 3) + (blockIdx.x >> 3);
    int plane = wid / nchp, chunk = wid - plane * nchp;
    int colth = threadIdx.x & 3;
    int slot = chunk * 64 + (threadIdx.x >> 2);
    if (slot >= N) return;
    int n = perm[slot];
    const __half* hp = hxw + (long long)plane * N * 32 + colth * 8;
    float dn = dis[n];
    float acc[8];
    {
        float sw = PRESC ? 1.0f : dn;
        float4 g = *(const float4*)&hp[n * 32];
        const __half2* hs = (const __half2*)&g;
#pragma unroll
        for (int k = 0; k < 4; ++k) {
            float2 f = __half22float2(hs[k]);
            acc[2 * k + 0] = f.x * sw;
            acc[2 * k + 1] = f.y * sw;
        }
    }
    int e = rowptr[n], e1 = rowptr[n + 1];
    for (; e + 7 < e1; e += 8) {
        int s[8];
        float4 g[8];
        float w[8];
#pragma unroll
        for (int j = 0; j < 8; ++j) s[j] = csrc[e + j];
        if (!PRESC) {
#pragma unroll
            for (int j = 0; j < 8; ++j) w[j] = dis[s[j]];
        }
#pragma unroll
        for (int j = 0; j < 8; ++j) g[j] = *(const float4*)&hp[s[j] * 32];
#pragma unroll
        for (int j = 0; j < 8; ++j) {
            const __half2* h = (const __half2*)&g[j];
#pragma unroll
            for (int k = 0; k < 4; ++k) {
                float2 f = __half22float2(h[k]);
                if (PRESC) { acc[2 * k] += f.x; acc[2 * k + 1] += f.y; }
                else {
                    acc[2 * k]     = fmaf(f.x, w[j], acc[2 * k]);
                    acc[2 * k + 1] = fmaf(f.y, w[j], acc[2 * k + 1]);
                }
            }
        }
    }
    for (; e + 3 < e1; e += 4) {
        int s[4];
        float4 g[4];
        float w[4];
#pragma unroll
        for (int j = 0; j < 4; ++j) s[j] = csrc[e + j];
        if (!PRESC) {
#pragma unroll
            for (int j = 0; j < 4; ++j) w[j] = dis[s[j]];
        }
#pragma unroll
        for (int j = 0; j < 4; ++j) g[j] = *(const float4*)&hp[s[j] * 32];
#pragma unroll
        for (int j = 0; j < 4; ++j) {
            const __half2* h = (const __half2*)&g[j];
#pragma unroll
            for (int k = 0; k < 4; ++k) {
                float2 f = __half22float2(h[k]);
                if (PRESC) { acc[2 * k] += f.x; acc[2 * k + 1] += f.y; }
                else {
                    acc[2 * k]     = fmaf(f.x, w[j], acc[2 * k]);
                    acc[2 * k + 1] = fmaf(f.y, w[j], acc[2 * k + 1]);
                }
            }
        }
    }
    for (; e < e1; ++e) {
        int s0 = csrc[e];
        float w0 = PRESC ? 1.0f : dis[s0];
        float4 g0 = *(const float4*)&hp[s0 * 32];
        const __half2* h = (const __half2*)&g0;
#pragma unroll
        for (int k = 0; k < 4; ++k) {
            float2 f = __half22float2(h[k]);
            acc[2 * k]     = fmaf(f.x, w0, acc[2 * k]);
            acc[2 * k + 1] = fmaf(f.y, w0, acc[2 * k + 1]);
        }
    }
    const int ch = plane * 32 + colth * 8;
    v8h o;
#pragma unroll
    for (int j = 0; j < 8; ++j)
        o[j] = (_Float16)fmaf(acc[j], dn, bias[ch + j]);
    *(v8h*)&outh[(long long)n * 96 + ch] = o;  // full 64-B aligned line write
}

// ---------------- BN stats over ROW-MAJOR fp16 buffer (R7-proven) -----------
// grid must be a multiple of 3 so stride = grid*256 is a multiple of 12.

__global__ __launch_bounds__(256) void bn_stats96h(const __half* __restrict__ h,
                                                   float* __restrict__ sums, int N) {
    __shared__ float sb[192];
    const int tid = threadIdx.x;
    if (tid < 192) sb[tid] = 0.0f;
    __syncthreads();
    int g = blockIdx.x * 256 + tid;
    int total = N * 12, stride = gridDim.x * 256;
    int c8 = g % 12;
    float s[8] = {0, 0, 0, 0, 0, 0, 0, 0};
    float q[8] = {0, 0, 0, 0, 0, 0, 0, 0};
    for (int i = g; i < total; i += stride) {
        int n = i / 12;
        float4 raw = *(const float4*)&h[n * 96 + 8 * c8];
        const __half2* hp = (const __half2*)&raw;
#pragma unroll
        for (int k = 0; k < 4; ++k) {
            float2 f = __half22float2(hp[k]);
            s[2 * k + 0] += f.x;
            s[2 * k + 1] += f.y;
            q[2 * k + 0] += f.x * f.x;
            q[2 * k + 1] += f.y * f.y;
        }
    }
#pragma unroll
    for (int j = 0; j < 8; ++j) {
        atomicAdd(&sb[8 * c8 + j], s[j]);
        atomicAdd(&sb[96 + 8 * c8 + j], q[j]);
    }
    __syncthreads();
    if (tid < 192) atomicAdd(&sums[tid], sb[tid]);
}

// ---------------- launch ----------------

extern "C" void kernel_launch(void* const* d_in, const int* in_sizes, int n_in,
                              void* d_out, int out_size, void* d_ws, size_t ws_size,
                              hipStream_t stream) {
    const float* x   = (const float*)d_in[0];
    const int*   ei  = (const int*)d_in[1];
    const float* W1  = (const float*)d_in[2];
    const float* b1  = (const float*)d_in[3];
    const float* g1  = (const float*)d_in[4];
    const float* be1 = (const float*)d_in[5];
    const float* W2  = (const float*)d_in[6];
    const float* b2  = (const float*)d_in[7];
    const float* g2  = (const float*)d_in[8];
    const float* be2 = (const float*)d_in[9];
    const float* Wp1 = (const float*)d_in[10];
    const float* bp1 = (const float*)d_in[11];
    const float* gp  = (const float*)d_in[12];
    const float* bep = (const float*)d_in[13];
    const float* Wp2 = (const float*)d_in[14];
    const float* bp2 = (const float*)d_in[15];

    const int N = in_sizes[0] / 128;   // 50000 (< 2^16 -> uint16 indices ok)
    const int E = in_sizes[1] / 2;     // 800000
    const int* src = ei;
    const int* dst = ei + E;

    // workspace layout (cnt/sums/ghist/gcur adjacent -> one memsetAsync)
    char* w = (char*)d_ws;
    auto alloc = [&](size_t bytes) { char* p = w; w += (bytes + 15) & ~size_t(15); return p; };
    int*            cnt    = (int*)alloc((size_t)N * 4);
    float*          sums   = (float*)alloc(576 * 4);
    int*            ghist  = (int*)alloc(64 * 4);
    int*            gcur   = (int*)alloc(64 * 4);
    int*            rowptr = (int*)alloc((size_t)(N + 1) * 4);
    int*            bsum   = (int*)alloc(64 * 4);
    float*          dis    = (float*)alloc((size_t)N * 4);
    unsigned short* eoff   = (unsigned short*)alloc((size_t)E * 2);
    unsigned short* csrc   = (unsigned short*)alloc((size_t)E * 2);
    unsigned short* perm   = (unsigned short*)alloc((size_t)N * 2);
    _Float16*       buf2h  = (_Float16*)alloc((size_t)N * 96 * 2);  // row-major
    _Float16*       hbuf   = (_Float16*)alloc((size_t)N * 96 * 2);  // superplane
    float* sums1 = sums, *sums2 = sums + 192, *sums3 = sums + 384;

    float* out = (float*)d_out;

    const int gE   = cdiv(E, BLK);                 // 3125 edge blocks
    const int gG   = cdiv(N, 64);                  // 782 gemm blocks
    const int nb   = cdiv(N, 1024);                // scan chunks (49)
    const int nchp = (cdiv(N, 64) + 7) & ~7;       // 784 chunks/plane (pad %8)
    const int gAgg = 3 * nchp;                     // 2352 (divisible by 8)

    // zero cnt + BN sums + ghist + gcur (adjacent -> single contiguous memset)
    size_t zlen = (size_t)((char*)gcur - (char*)cnt) + 64 * 4;
    hipMemsetAsync(cnt, 0, zlen, stream);

    // D1: layer-1 GEMM (superplane fp16 shadow, unscaled)
    gemm96m<128, false, false, false, true, float><<<gG, 256, 0, stream>>>(
        x, W1, nullptr, nullptr, nullptr, nullptr, nullptr, hbuf, nullptr, N);
    // D2: in-degree count (standalone: 0 LDS -> full occupancy, R10 lesson)
    count_dst_off<<<gE, BLK, 0, stream>>>(dst, cnt, eoff, E);
    // D3-D5: CSR build + degree-sort perm (hist in scan1; prefix+scatter in scan23)
    scan1_dis<<<nb, 256, 0, stream>>>(cnt, rowptr, bsum, dis, ghist, N);
    scan23<<<cdiv(N, 256), 256, 0, stream>>>(rowptr, bsum, cnt, ghist, gcur, perm,
                                             nb, N, E);
    csr_fill<<<gE, BLK, 0, stream>>>(src, dst, eoff, rowptr, csrc, E);

    // D6-D7: layer-1 agg (degree-balanced waves) -> row-major buf2h; BN1 stats
    agg32p<false><<<gAgg, 256, 0, stream>>>((const __half*)hbuf, rowptr, csrc, dis,
                                            b1, perm, buf2h, nchp, N);
    bn_stats96h<<<510, 256, 0, stream>>>((const __half*)buf2h, sums1, N);

    // D8-D10: layer 2 (BN1 fused, row-major in; prescaled superplane out) + agg
    gemm96m<96, true, false, false, true, _Float16><<<gG, 256, 0, stream>>>(
        buf2h, W2, nullptr, sums1, g1, be1, dis, hbuf, nullptr, N);
    agg32p<true><<<gAgg, 256, 0, stream>>>((const __half*)hbuf, rowptr, csrc, dis,
                                           b2, perm, buf2h, nchp, N);
    bn_stats96h<<<510, 256, 0, stream>>>((const __half*)buf2h, sums2, N);

    // D11: projector linear 1 (BN2 fused; ROW-MAJOR fp16 out; BN3 stats fused)
    gemm96m<96, true, true, true, false, _Float16><<<gG, 256, 0, stream>>>(
        buf2h, Wp1, bp1, sums2, g2, be2, nullptr, hbuf, sums3, N);

    // D12: projector linear 2 (BN3 fused + bias + L2 normalize), row-major in
    gemm_finalm<<<gG, 256, 0, stream>>>(hbuf, Wp2, bp2, sums3, gp, bep, out, N);
}

// Round 12
// 345.389 us; speedup vs baseline: 1.2929x; 1.2929x over previous
//
#include <hip/hip_runtime.h>
#include <hip/hip_fp16.h>

constexpr int BLK = 256;

static inline int cdiv(long long a, int b) { return (int)((a + b - 1) / b); }

using v8h = __attribute__((ext_vector_type(8))) _Float16;
using v4f = __attribute__((ext_vector_type(4))) float;

// ---------------- layout / scheduling notes (R7-R11 post-mortems) ----------
// hbuf (GEMM->agg shadow): SUPERPLANE-32 = 3 planes x [N][32]; (n,c) at
//   [(c>>5)*N + n]*32 + (c&31). XCD-affine plane-major agg blocks -> gather
//   working set ~3.2MB/XCD, L2-resident (R8: FETCH 89.6->14.6MB).
// buf2h / proj1 out: ROW-MAJOR [N][96] fp16 (streaming consumers, R9 lesson).
// R10: agg is latency/issue bound; degree-sorted perm balances wave edge loops.
// R11: NEVER per-item global atomic tickets on few addresses (50K atomics on
//   64 addrs = 108us). Block-aggregate in LDS first; one global atomic per
//   (block,bucket). R4: grid.sync ~60us — never. R5: no spin-waits.
// R6: launch overhead ~2us/dispatch — kernel time is what matters.

// ---------------- degree / CSR build ----------------

// count in-degree; record per-edge within-node offset as uint16 (deg < 64K)
__global__ void count_dst_off(const int* __restrict__ dst, int* __restrict__ cnt,
                              unsigned short* __restrict__ eoff, int E) {
    for (int i = blockIdx.x * blockDim.x + threadIdx.x; i < E; i += gridDim.x * blockDim.x)
        eoff[i] = (unsigned short)atomicAdd(&cnt[dst[i]], 1);
}

// block scans 1024 elements (256 threads x 4); emits dis = rsqrt(cnt+1);
// also accumulates a 64-bucket degree histogram (clamped) into ghist.
__global__ __launch_bounds__(256) void scan1_dis(const int* __restrict__ cnt,
                                                 int* __restrict__ rowptr,
                                                 int* __restrict__ bsum,
                                                 float* __restrict__ dis,
                                                 int* __restrict__ ghist, int N) {
    __shared__ int ts[256];
    __shared__ int lh[64];
    int tid = threadIdx.x;
    if (tid < 64) lh[tid] = 0;
    int base = blockIdx.x * 1024 + tid * 4;
    int v[4], s = 0;
#pragma unroll
    for (int i = 0; i < 4; ++i) {
        v[i] = (base + i < N) ? cnt[base + i] : 0;
        s += v[i];
        if (base + i < N) dis[base + i] = rsqrtf((float)v[i] + 1.0f);
    }
    ts[tid] = s;
    __syncthreads();  // lh zeroing + ts visible
#pragma unroll
    for (int i = 0; i < 4; ++i) {
        if (base + i < N) atomicAdd(&lh[v[i] < 63 ? v[i] : 63], 1);
    }
    for (int off = 1; off < 256; off <<= 1) {
        int t = 0;
        if (tid >= off) t = ts[tid - off];
        __syncthreads();
        if (tid >= off) ts[tid] += t;
        __syncthreads();
    }
    int run = ts[tid] - s;
#pragma unroll
    for (int i = 0; i < 4; ++i) {
        if (base + i < N) rowptr[base + i] = run;
        run += v[i];
    }
    if (tid == 255) bsum[blockIdx.x] = ts[255];
    __syncthreads();  // all lh atomics complete
    if (tid < 64) {
        int c = lh[tid];
        if (c) atomicAdd(&ghist[tid], c);
    }
}

// merged scan2+scan3 + degree-sort scatter (block-aggregated ticketing):
// wave 0 scans the <=64 chunk sums; wave 1 scans the 64-bucket histogram;
// lanes 128..191 zero the block-local bucket counters. Each node then ranks
// itself within the block via LDS atomic; threads 0-63 claim a contiguous
// global range per bucket with ONE atomicAdd each (R11 lesson: per-node
// global tickets on 64 addresses serialized at ~108us).
__global__ __launch_bounds__(256) void scan23(int* __restrict__ rowptr,
                                              const int* __restrict__ bsum,
                                              const int* __restrict__ cnt,
                                              const int* __restrict__ ghist,
                                              int* __restrict__ gcur,
                                              unsigned short* __restrict__ perm,
                                              int nb, int N, int E) {
    __shared__ int sboff[64];
    __shared__ int gb[64];
    __shared__ int lh[64];
    __shared__ int lbase[64];
    const int tid = threadIdx.x;
    if (tid < 64) {
        int orig = (tid < nb) ? bsum[tid] : 0;
        int v = orig;
#pragma unroll
        for (int off = 1; off < 64; off <<= 1) {
            int t = __shfl_up(v, off, 64);
            if (tid >= off) v += t;
        }
        sboff[tid] = v - orig;  // exclusive prefix of chunk sums
    } else if (tid < 128) {
        int b = tid - 64;       // lane b of wave 1
        int h = ghist[b];
        int v = h;
#pragma unroll
        for (int off = 1; off < 64; off <<= 1) {
            int t = __shfl_up(v, off, 64);
            if (b >= off) v += t;
        }
        gb[b] = v - h;          // exclusive prefix of degree buckets
    } else if (tid < 192) {
        lh[tid - 128] = 0;
    }
    __syncthreads();
    int i = blockIdx.x * 256 + tid;
    const bool valid = i < N;
    int d = 0, lrank = 0;
    if (valid) {
        rowptr[i] += sboff[i >> 10];
        d = cnt[i];
        d = d < 63 ? d : 63;
        lrank = atomicAdd(&lh[d], 1);   // LDS ticket (on-CU, fast)
    }
    __syncthreads();
    if (tid < 64) {
        int c = lh[tid];
        lbase[tid] = c ? atomicAdd(&gcur[tid], c) : 0;  // one global atomic
    }
    __syncthreads();
    if (valid) perm[gb[d] + lbase[d] + lrank] = (unsigned short)i;
    if (i == 0) rowptr[N] = E;
}

// atomic-free scatter of 2-B src index: slot = rowptr[dst] + eoff (bijection)
__global__ void csr_fill(const int* __restrict__ src, const int* __restrict__ dst,
                         const unsigned short* __restrict__ eoff,
                         const int* __restrict__ rowptr,
                         unsigned short* __restrict__ csrc, int E) {
    for (int i = blockIdx.x * blockDim.x + threadIdx.x; i < E; i += gridDim.x * blockDim.x) {
        csrc[rowptr[dst[i]] + (int)eoff[i]] = (unsigned short)src[i];
    }
}

// ---------------- MFMA GEMM body: act(in)[N,K] @ W[K,96] (+bias) ------------
// TIN=float: row-major fp32 input (layer 1). TIN=_Float16: ROW-MAJOR fp16.
// OUTSP=true: fp16 SUPERPLANE-32 output (feeds agg). false: row-major fp16.
// Optional pre-scale by dsc[row]. STATS: column sum/sumsq (fp32) into osums.

template <int K, bool ACT, bool BIAS, bool STATS, bool OUTSP, typename TIN>
__device__ __forceinline__ void gemm96_body(int bid,
                                            const TIN* __restrict__ in,
                                            const float* __restrict__ W,
                                            const float* __restrict__ bias,
                                            const float* __restrict__ bnsums,
                                            const float* __restrict__ gamma,
                                            const float* __restrict__ beta,
                                            const float* __restrict__ dsc,
                                            _Float16* __restrict__ hout,
                                            float* __restrict__ osums, int N) {
    constexpr int NK = K / 32;
    constexpr int LDK = K + 8;
    __shared__ __align__(16) _Float16 Wt[96 * LDK];
    __shared__ __align__(16) float ssl[ACT ? 192 : 1];
    __shared__ float sb[STATS ? 192 : 1];
    const int tid = threadIdx.x;
    for (int idx = tid; idx < K * 96; idx += 256) {
        int k = idx / 96, n = idx - k * 96;
        Wt[n * LDK + k] = (_Float16)W[idx];
    }
    if (ACT && tid < 96) {
        float inv_n = 1.0f / (float)N;
        float mean = bnsums[tid] * inv_n;
        float var = bnsums[96 + tid] * inv_n - mean * mean;
        float sc = gamma[tid] * rsqrtf(var + 1e-5f);
        ssl[tid] = sc;
        ssl[96 + tid] = beta[tid] - mean * sc;
    }
    if (STATS && tid < 192) sb[tid] = 0.0f;
    __syncthreads();

    const int wave = tid >> 6, lane = tid & 63;
    const int quad = lane >> 4, lm = lane & 15;
    const int rbase = bid * 64 + wave * 16;
    int arow = rbase + lm;
    arow = arow < N ? arow : N - 1;

    v8h afr[NK];
#pragma unroll
    for (int kc = 0; kc < NK; ++kc) {
        const int kk = kc * 32 + quad * 8;
        if constexpr (sizeof(TIN) == 4) {
            const float* p = (const float*)&in[(long long)arow * K + kk];
            float4 p0 = *(const float4*)p;
            float4 p1 = *(const float4*)(p + 4);
            if (ACT) {
                float4 sc0 = *(const float4*)&ssl[kk];
                float4 sc1 = *(const float4*)&ssl[kk + 4];
                float4 sh0 = *(const float4*)&ssl[96 + kk];
                float4 sh1 = *(const float4*)&ssl[96 + kk + 4];
                p0.x = fmaxf(fmaf(p0.x, sc0.x, sh0.x), 0.0f);
                p0.y = fmaxf(fmaf(p0.y, sc0.y, sh0.y), 0.0f);
                p0.z = fmaxf(fmaf(p0.z, sc0.z, sh0.z), 0.0f);
                p0.w = fmaxf(fmaf(p0.w, sc0.w, sh0.w), 0.0f);
                p1.x = fmaxf(fmaf(p1.x, sc1.x, sh1.x), 0.0f);
                p1.y = fmaxf(fmaf(p1.y, sc1.y, sh1.y), 0.0f);
                p1.z = fmaxf(fmaf(p1.z, sc1.z, sh1.z), 0.0f);
                p1.w = fmaxf(fmaf(p1.w, sc1.w, sh1.w), 0.0f);
            }
            v8h a;
            a[0] = (_Float16)p0.x; a[1] = (_Float16)p0.y;
            a[2] = (_Float16)p0.z; a[3] = (_Float16)p0.w;
            a[4] = (_Float16)p1.x; a[5] = (_Float16)p1.y;
            a[6] = (_Float16)p1.z; a[7] = (_Float16)p1.w;
            afr[kc] = a;
        } else {
            // row-major fp16 read: 16-B contiguous per lane, 192-B rows (R7)
            v8h hv = *(const v8h*)&in[(long long)arow * 96 + kk];
            if (ACT) {
#pragma unroll
                for (int j = 0; j < 8; ++j) {
                    float f = (float)hv[j];
                    f = fmaxf(fmaf(f, ssl[kk + j], ssl[96 + kk + j]), 0.0f);
                    hv[j] = (_Float16)f;
                }
            }
            afr[kc] = hv;
        }
    }

    v4f acc[6];
#pragma unroll
    for (int t = 0; t < 6; ++t) {
        v4f c = {0.0f, 0.0f, 0.0f, 0.0f};
#pragma unroll
        for (int kc = 0; kc < NK; ++kc) {
            v8h b = *(const v8h*)&Wt[(t * 16 + lm) * LDK + kc * 32 + quad * 8];
            c = __builtin_amdgcn_mfma_f32_16x16x32_f16(afr[kc], b, c, 0, 0, 0);
        }
        acc[t] = c;
    }

    float dr[4];
#pragma unroll
    for (int r = 0; r < 4; ++r) {
        int gr = rbase + quad * 4 + r;
        dr[r] = dsc ? dsc[gr < N ? gr : N - 1] : 1.0f;
    }

    float ls[6], lq[6];
#pragma unroll
    for (int t = 0; t < 6; ++t) { ls[t] = 0.0f; lq[t] = 0.0f; }
#pragma unroll
    for (int t = 0; t < 6; ++t) {
        float bv = BIAS ? bias[t * 16 + lm] : 0.0f;
#pragma unroll
        for (int r = 0; r < 4; ++r) {
            int gr = rbase + quad * 4 + r;
            if (gr < N) {
                float o = acc[t][r] + bv;
                if (OUTSP) {
                    // superplane: plane = t>>1, within-plane col = (t&1)*16+lm
                    hout[(((long long)(t >> 1) * N + gr) * 32) + (t & 1) * 16 + lm] =
                        (_Float16)(o * dr[r]);
                } else {
                    hout[(long long)gr * 96 + t * 16 + lm] = (_Float16)(o * dr[r]);
                }
                if (STATS) { ls[t] += o; lq[t] += o * o; }
            }
        }
    }
    if (STATS) {
#pragma unroll
        for (int t = 0; t < 6; ++t) {
            ls[t] += __shfl_xor(ls[t], 16);
            ls[t] += __shfl_xor(ls[t], 32);
            lq[t] += __shfl_xor(lq[t], 16);
            lq[t] += __shfl_xor(lq[t], 32);
        }
        if (quad == 0) {
#pragma unroll
            for (int t = 0; t < 6; ++t) {
                atomicAdd(&sb[t * 16 + lm], ls[t]);
                atomicAdd(&sb[96 + t * 16 + lm], lq[t]);
            }
        }
        __syncthreads();
        if (tid < 192) atomicAdd(&osums[tid], sb[tid]);
    }
}

template <int K, bool ACT, bool BIAS, bool STATS, bool OUTSP, typename TIN>
__global__ __launch_bounds__(256) void gemm96m(const TIN* __restrict__ in,
                                               const float* __restrict__ W,
                                               const float* __restrict__ bias,
                                               const float* __restrict__ bnsums,
                                               const float* __restrict__ gamma,
                                               const float* __restrict__ beta,
                                               const float* __restrict__ dsc,
                                               _Float16* __restrict__ hout,
                                               float* __restrict__ osums, int N) {
    gemm96_body<K, ACT, BIAS, STATS, OUTSP, TIN>(blockIdx.x, in, W, bias, bnsums,
                                                 gamma, beta, dsc, hout, osums, N);
}

// ---------------- MFMA final GEMM: l2norm(act(in) @ Wp2[96,64] + bp2) -------
// in: ROW-MAJOR fp16 (R7-proven form).

__global__ __launch_bounds__(256) void gemm_finalm(const _Float16* __restrict__ in,
                                                   const float* __restrict__ W,
                                                   const float* __restrict__ bias,
                                                   const float* __restrict__ bnsums,
                                                   const float* __restrict__ gamma,
                                                   const float* __restrict__ beta,
                                                   float* __restrict__ out, int N) {
    constexpr int K = 96, NK = 3, LDK = K + 8;
    __shared__ __align__(16) _Float16 Wt[64 * LDK];
    __shared__ __align__(16) float ssl[192];
    const int tid = threadIdx.x;
    for (int idx = tid; idx < K * 64; idx += 256) {
        int k = idx / 64, n = idx - k * 64;
        Wt[n * LDK + k] = (_Float16)W[idx];
    }
    if (tid < 96) {
        float inv_n = 1.0f / (float)N;
        float mean = bnsums[tid] * inv_n;
        float var = bnsums[96 + tid] * inv_n - mean * mean;
        float sc = gamma[tid] * rsqrtf(var + 1e-5f);
        ssl[tid] = sc;
        ssl[96 + tid] = beta[tid] - mean * sc;
    }
    __syncthreads();

    const int wave = tid >> 6, lane = tid & 63;
    const int quad = lane >> 4, lm = lane & 15;
    const int rbase = blockIdx.x * 64 + wave * 16;
    int arow = rbase + lm;
    arow = arow < N ? arow : N - 1;

    v8h afr[NK];
#pragma unroll
    for (int kc = 0; kc < NK; ++kc) {
        const int kk = kc * 32 + quad * 8;
        v8h hv = *(const v8h*)&in[(long long)arow * 96 + kk];
#pragma unroll
        for (int j = 0; j < 8; ++j) {
            float f = (float)hv[j];
            f = fmaxf(fmaf(f, ssl[kk + j], ssl[96 + kk + j]), 0.0f);
            hv[j] = (_Float16)f;
        }
        afr[kc] = hv;
    }

    v4f acc[4];
#pragma unroll
    for (int t = 0; t < 4; ++t) {
        v4f c = {0.0f, 0.0f, 0.0f, 0.0f};
#pragma unroll
        for (int kc = 0; kc < NK; ++kc) {
            v8h b = *(const v8h*)&Wt[(t * 16 + lm) * LDK + kc * 32 + quad * 8];
            c = __builtin_amdgcn_mfma_f32_16x16x32_f16(afr[kc], b, c, 0, 0, 0);
        }
        float bv = bias[t * 16 + lm];
        c[0] += bv; c[1] += bv; c[2] += bv; c[3] += bv;
        acc[t] = c;
    }

    float sq[4];
#pragma unroll
    for (int r = 0; r < 4; ++r) {
        float s = acc[0][r] * acc[0][r] + acc[1][r] * acc[1][r] +
                  acc[2][r] * acc[2][r] + acc[3][r] * acc[3][r];
#pragma unroll
        for (int m = 1; m < 16; m <<= 1) s += __shfl_xor(s, m, 64);
        sq[r] = 1.0f / fmaxf(sqrtf(s), 1e-12f);
    }
#pragma unroll
    for (int r = 0; r < 4; ++r) {
        int gr = rbase + quad * 4 + r;
        if (gr < N) {
#pragma unroll
            for (int t = 0; t < 4; ++t)
                out[(long long)gr * 64 + t * 16 + lm] = acc[t][r] * sq[r];
        }
    }
}

// ---------------- CSR pull aggregation: superplane in, row-major out ---------
// Block = 64 perm-slots x 4 col-threads for one plane (4 lanes of a node read
// one contiguous 64-B line per edge). Plane-major wid + %8 bijective swizzle
// -> XCD-local 3.2MB plane (L2-resident, R8). Nodes taken via degree-sorted
// perm so the 16 nodes of a wave have similar degree -> balanced edge loops.
// PRESC=true : rows pre-scaled by dis[src] -> out = b + dn*(h[n] + sum h[s])
// PRESC=false: acc = dn*h[n] + sum dis[s]*h[s]; out = b + dn*acc

template <bool PRESC>
__global__ __launch_bounds__(256) void agg32p(const __half* __restrict__ hxw,
                                              const int* __restrict__ rowptr,
                                              const unsigned short* __restrict__ csrc,
                                              const float* __restrict__ dis,
                                              const float* __restrict__ bias,
                                              const unsigned short* __restrict__ perm,
                                              _Float16* __restrict__ outh,
                                              int nchp, int N) {
    int nwg = gridDim.x;  // 3*nchp, divisible by 8
    int wid = (blockIdx.x & 7) * (nwg >> 3) + (blockIdx.x >> 3);
    int plane = wid / nchp, chunk = wid - plane * nchp;
    int colth = threadIdx.x & 3;
    int slot = chunk * 64 + (threadIdx.x >> 2);
    if (slot >= N) return;
    int n = perm[slot];
    const __half* hp = hxw + (long long)plane * N * 32 + colth * 8;
    float dn = dis[n];
    float acc[8];
    {
        float sw = PRESC ? 1.0f : dn;
        float4 g = *(const float4*)&hp[n * 32];
        const __half2* hs = (const __half2*)&g;
#pragma unroll
        for (int k = 0; k < 4; ++k) {
            float2 f = __half22float2(hs[k]);
            acc[2 * k + 0] = f.x * sw;
            acc[2 * k + 1] = f.y * sw;
        }
    }
    int e = rowptr[n], e1 = rowptr[n + 1];
    for (; e + 7 < e1; e += 8) {
        int s[8];
        float4 g[8];
        float w[8];
#pragma unroll
        for (int j = 0; j < 8; ++j) s[j] = csrc[e + j];
        if (!PRESC) {
#pragma unroll
            for (int j = 0; j < 8; ++j) w[j] = dis[s[j]];
        }
#pragma unroll
        for (int j = 0; j < 8; ++j) g[j] = *(const float4*)&hp[s[j] * 32];
#pragma unroll
        for (int j = 0; j < 8; ++j) {
            const __half2* h = (const __half2*)&g[j];
#pragma unroll
            for (int k = 0; k < 4; ++k) {
                float2 f = __half22float2(h[k]);
                if (PRESC) { acc[2 * k] += f.x; acc[2 * k + 1] += f.y; }
                else {
                    acc[2 * k]     = fmaf(f.x, w[j], acc[2 * k]);
                    acc[2 * k + 1] = fmaf(f.y, w[j], acc[2 * k + 1]);
                }
            }
        }
    }
    for (; e + 3 < e1; e += 4) {
        int s[4];
        float4 g[4];
        float w[4];
#pragma unroll
        for (int j = 0; j < 4; ++j) s[j] = csrc[e + j];
        if (!PRESC) {
#pragma unroll
            for (int j = 0; j < 4; ++j) w[j] = dis[s[j]];
        }
#pragma unroll
        for (int j = 0; j < 4; ++j) g[j] = *(const float4*)&hp[s[j] * 32];
#pragma unroll
        for (int j = 0; j < 4; ++j) {
            const __half2* h = (const __half2*)&g[j];
#pragma unroll
            for (int k = 0; k < 4; ++k) {
                float2 f = __half22float2(h[k]);
                if (PRESC) { acc[2 * k] += f.x; acc[2 * k + 1] += f.y; }
                else {
                    acc[2 * k]     = fmaf(f.x, w[j], acc[2 * k]);
                    acc[2 * k + 1] = fmaf(f.y, w[j], acc[2 * k + 1]);
                }
            }
        }
    }
    for (; e < e1; ++e) {
        int s0 = csrc[e];
        float w0 = PRESC ? 1.0f : dis[s0];
        float4 g0 = *(const float4*)&hp[s0 * 32];
        const __half2* h = (const __half2*)&g0;
#pragma unroll
        for (int k = 0; k < 4; ++k) {
            float2 f = __half22float2(h[k]);
            acc[2 * k]     = fmaf(f.x, w0, acc[2 * k]);
            acc[2 * k + 1] = fmaf(f.y, w0, acc[2 * k + 1]);
        }
    }
    const int ch = plane * 32 + colth * 8;
    v8h o;
#pragma unroll
    for (int j = 0; j < 8; ++j)
        o[j] = (_Float16)fmaf(acc[j], dn, bias[ch + j]);
    *(v8h*)&outh[(long long)n * 96 + ch] = o;  // full 64-B aligned line write
}

// ---------------- BN stats over ROW-MAJOR fp16 buffer (R7-proven) -----------
// grid must be a multiple of 3 so stride = grid*256 is a multiple of 12.

__global__ __launch_bounds__(256) void bn_stats96h(const __half* __restrict__ h,
                                                   float* __restrict__ sums, int N) {
    __shared__ float sb[192];
    const int tid = threadIdx.x;
    if (tid < 192) sb[tid] = 0.0f;
    __syncthreads();
    int g = blockIdx.x * 256 + tid;
    int total = N * 12, stride = gridDim.x * 256;
    int c8 = g % 12;
    float s[8] = {0, 0, 0, 0, 0, 0, 0, 0};
    float q[8] = {0, 0, 0, 0, 0, 0, 0, 0};
    for (int i = g; i < total; i += stride) {
        int n = i / 12;
        float4 raw = *(const float4*)&h[n * 96 + 8 * c8];
        const __half2* hp = (const __half2*)&raw;
#pragma unroll
        for (int k = 0; k < 4; ++k) {
            float2 f = __half22float2(hp[k]);
            s[2 * k + 0] += f.x;
            s[2 * k + 1] += f.y;
            q[2 * k + 0] += f.x * f.x;
            q[2 * k + 1] += f.y * f.y;
        }
    }
#pragma unroll
    for (int j = 0; j < 8; ++j) {
        atomicAdd(&sb[8 * c8 + j], s[j]);
        atomicAdd(&sb[96 + 8 * c8 + j], q[j]);
    }
    __syncthreads();
    if (tid < 192) atomicAdd(&sums[tid], sb[tid]);
}

// ---------------- launch ----------------

extern "C" void kernel_launch(void* const* d_in, const int* in_sizes, int n_in,
                              void* d_out, int out_size, void* d_ws, size_t ws_size,
                              hipStream_t stream) {
    const float* x   = (const float*)d_in[0];
    const int*   ei  = (const int*)d_in[1];
    const float* W1  = (const float*)d_in[2];
    const float* b1  = (const float*)d_in[3];
    const float* g1  = (const float*)d_in[4];
    const float* be1 = (const float*)d_in[5];
    const float* W2  = (const float*)d_in[6];
    const float* b2  = (const float*)d_in[7];
    const float* g2  = (const float*)d_in[8];
    const float* be2 = (const float*)d_in[9];
    const float* Wp1 = (const float*)d_in[10];
    const float* bp1 = (const float*)d_in[11];
    const float* gp  = (const float*)d_in[12];
    const float* bep = (const float*)d_in[13];
    const float* Wp2 = (const float*)d_in[14];
    const float* bp2 = (const float*)d_in[15];

    const int N = in_sizes[0] / 128;   // 50000 (< 2^16 -> uint16 indices ok)
    const int E = in_sizes[1] / 2;     // 800000
    const int* src = ei;
    const int* dst = ei + E;

    // workspace layout (cnt/sums/ghist/gcur adjacent -> one memsetAsync)
    char* w = (char*)d_ws;
    auto alloc = [&](size_t bytes) { char* p = w; w += (bytes + 15) & ~size_t(15); return p; };
    int*            cnt    = (int*)alloc((size_t)N * 4);
    float*          sums   = (float*)alloc(576 * 4);
    int*            ghist  = (int*)alloc(64 * 4);
    int*            gcur   = (int*)alloc(64 * 4);
    int*            rowptr = (int*)alloc((size_t)(N + 1) * 4);
    int*            bsum   = (int*)alloc(64 * 4);
    float*          dis    = (float*)alloc((size_t)N * 4);
    unsigned short* eoff   = (unsigned short*)alloc((size_t)E * 2);
    unsigned short* csrc   = (unsigned short*)alloc((size_t)E * 2);
    unsigned short* perm   = (unsigned short*)alloc((size_t)N * 2);
    _Float16*       buf2h  = (_Float16*)alloc((size_t)N * 96 * 2);  // row-major
    _Float16*       hbuf   = (_Float16*)alloc((size_t)N * 96 * 2);  // superplane
    float* sums1 = sums, *sums2 = sums + 192, *sums3 = sums + 384;

    float* out = (float*)d_out;

    const int gE   = cdiv(E, BLK);                 // 3125 edge blocks
    const int gG   = cdiv(N, 64);                  // 782 gemm blocks
    const int nb   = cdiv(N, 1024);                // scan chunks (49)
    const int nchp = (cdiv(N, 64) + 7) & ~7;       // 784 chunks/plane (pad %8)
    const int gAgg = 3 * nchp;                     // 2352 (divisible by 8)

    // zero cnt + BN sums + ghist + gcur (adjacent -> single contiguous memset)
    size_t zlen = (size_t)((char*)gcur - (char*)cnt) + 64 * 4;
    hipMemsetAsync(cnt, 0, zlen, stream);

    // D1: layer-1 GEMM (superplane fp16 shadow, unscaled)
    gemm96m<128, false, false, false, true, float><<<gG, 256, 0, stream>>>(
        x, W1, nullptr, nullptr, nullptr, nullptr, nullptr, hbuf, nullptr, N);
    // D2: in-degree count (standalone: 0 LDS -> full occupancy, R10 lesson)
    count_dst_off<<<gE, BLK, 0, stream>>>(dst, cnt, eoff, E);
    // D3-D5: CSR build + degree-sort perm (hist in scan1; prefix+scatter in scan23)
    scan1_dis<<<nb, 256, 0, stream>>>(cnt, rowptr, bsum, dis, ghist, N);
    scan23<<<cdiv(N, 256), 256, 0, stream>>>(rowptr, bsum, cnt, ghist, gcur, perm,
                                             nb, N, E);
    csr_fill<<<gE, BLK, 0, stream>>>(src, dst, eoff, rowptr, csrc, E);

    // D6-D7: layer-1 agg (degree-balanced waves) -> row-major buf2h; BN1 stats
    agg32p<false><<<gAgg, 256, 0, stream>>>((const __half*)hbuf, rowptr, csrc, dis,
                                            b1, perm, buf2h, nchp, N);
    bn_stats96h<<<510, 256, 0, stream>>>((const __half*)buf2h, sums1, N);

    // D8-D10: layer 2 (BN1 fused, row-major in; prescaled superplane out) + agg
    gemm96m<96, true, false, false, true, _Float16><<<gG, 256, 0, stream>>>(
        buf2h, W2, nullptr, sums1, g1, be1, dis, hbuf, nullptr, N);
    agg32p<true><<<gAgg, 256, 0, stream>>>((const __half*)hbuf, rowptr, csrc, dis,
                                           b2, perm, buf2h, nchp, N);
    bn_stats96h<<<510, 256, 0, stream>>>((const __half*)buf2h, sums2, N);

    // D11: projector linear 1 (BN2 fused; ROW-MAJOR fp16 out; BN3 stats fused)
    gemm96m<96, true, true, true, false, _Float16><<<gG, 256, 0, stream>>>(
        buf2h, Wp1, bp1, sums2, g2, be2, nullptr, hbuf, sums3, N);

    // D12: projector linear 2 (BN3 fused + bias + L2 normalize), row-major in
    gemm_finalm<<<gG, 256, 0, stream>>>(hbuf, Wp2, bp2, sums3, gp, bep, out, N);
}

// Round 13
// 309.391 us; speedup vs baseline: 1.4433x; 1.1164x over previous
//
#include <hip/hip_runtime.h>
#include <hip/hip_fp16.h>

constexpr int BLK = 256;

static inline int cdiv(long long a, int b) { return (int)((a + b - 1) / b); }

using v8h = __attribute__((ext_vector_type(8))) _Float16;
using v4f = __attribute__((ext_vector_type(4))) float;

// ---------------- configuration ledger (R0-R12) ----------------
// This is the R7 configuration — empirical best (308.2us). Lessons baked in:
// R2: never bolt epilogues onto the latency-bound agg loop (VGPR collapse).
// R4: cooperative grid.sync ~60us each on MI355X — never use.
// R5: no cross-block spin-waits (container-killing hang risk).
// R6: launch overhead ~2us/dispatch — kernel time matters, not count.
// R7: fp16 activations (halve streaming) + count overlapped with gemm1 = win.
// R8/R9: planar/superplane layouts fix agg FETCH (89.6->14.6MB) but NOT time
//   (~40us in every layout) -> agg is latency-bound at the HW wave cap, and
//   non-row-major consumers cost +11us -> row-major everywhere is best.
// R10: splitting count from gemm1 is neutral; keep merged.
// R11: per-item global atomic tickets on few addresses = 108us. Never.
// R12: degree-sorted perm randomizes rowptr/dis/csrc/output locality
//   (FETCH +45MB, agg +5-7us) — scheduling permutation loses to locality.

// ---------------- degree / CSR build ----------------

// block scans 1024 elements (256 threads x 4); also emits dis = rsqrt(cnt+1)
__global__ __launch_bounds__(256) void scan1_dis(const int* __restrict__ cnt,
                                                 int* __restrict__ rowptr,
                                                 int* __restrict__ bsum,
                                                 float* __restrict__ dis, int N) {
    __shared__ int ts[256];
    int tid = threadIdx.x;
    int base = blockIdx.x * 1024 + tid * 4;
    int v[4], s = 0;
#pragma unroll
    for (int i = 0; i < 4; ++i) {
        v[i] = (base + i < N) ? cnt[base + i] : 0;
        s += v[i];
        if (base + i < N) dis[base + i] = rsqrtf((float)v[i] + 1.0f);
    }
    ts[tid] = s;
    __syncthreads();
    for (int off = 1; off < 256; off <<= 1) {
        int t = 0;
        if (tid >= off) t = ts[tid - off];
        __syncthreads();
        if (tid >= off) ts[tid] += t;
        __syncthreads();
    }
    int run = ts[tid] - s;
#pragma unroll
    for (int i = 0; i < 4; ++i) {
        if (base + i < N) rowptr[base + i] = run;
        run += v[i];
    }
    if (tid == 255) bsum[blockIdx.x] = ts[255];
}

// merged scan2+scan3: every block wave-scans the <=64 chunk sums (L2-resident,
// redundant but free) and applies its chunk's exclusive offset to rowptr.
__global__ __launch_bounds__(256) void scan23(int* __restrict__ rowptr,
                                              const int* __restrict__ bsum,
                                              int nb, int N, int E) {
    __shared__ int sboff[64];
    const int tid = threadIdx.x;
    if (tid < 64) {
        int orig = (tid < nb) ? bsum[tid] : 0;
        int v = orig;
#pragma unroll
        for (int off = 1; off < 64; off <<= 1) {
            int t = __shfl_up(v, off, 64);
            if (tid >= off) v += t;
        }
        sboff[tid] = v - orig;  // exclusive prefix of chunk sums
    }
    __syncthreads();
    int i = blockIdx.x * 256 + tid;
    if (i < N) rowptr[i] += sboff[i >> 10];
    if (i == 0) rowptr[N] = E;
}

// atomic-free scatter of 2-B src index: slot = rowptr[dst] + eoff (bijection)
__global__ void csr_fill(const int* __restrict__ src, const int* __restrict__ dst,
                         const unsigned short* __restrict__ eoff,
                         const int* __restrict__ rowptr,
                         unsigned short* __restrict__ csrc, int E) {
    for (int i = blockIdx.x * blockDim.x + threadIdx.x; i < E; i += gridDim.x * blockDim.x) {
        csrc[rowptr[dst[i]] + (int)eoff[i]] = (unsigned short)src[i];
    }
}

// ---------------- MFMA GEMM body: act(in)[N,K] @ W[K,96] (+bias) ------------
// TIN = float (layer 1, raw x) or _Float16 (fp16 activation buffers).
// A: load -> (BN+ReLU in fp32) -> fp16 frags. B: W^T fp16 in LDS (one barrier).
// Output: ALWAYS fp16 (hout), optionally pre-scaled by dsc[row] (nullable).
// STATS: epilogue accumulates column sum/sumsq (fp32, pre-scale) into osums.

template <int K, bool ACT, bool BIAS, bool STATS, typename TIN>
__device__ __forceinline__ void gemm96_body(int bid,
                                            const TIN* __restrict__ in,
                                            const float* __restrict__ W,
                                            const float* __restrict__ bias,
                                            const float* __restrict__ bnsums,
                                            const float* __restrict__ gamma,
                                            const float* __restrict__ beta,
                                            const float* __restrict__ dsc,
                                            _Float16* __restrict__ hout,
                                            float* __restrict__ osums, int N) {
    constexpr int NK = K / 32;
    constexpr int LDK = K + 8;
    __shared__ __align__(16) _Float16 Wt[96 * LDK];
    __shared__ __align__(16) float ssl[ACT ? 192 : 1];
    __shared__ float sb[STATS ? 192 : 1];
    const int tid = threadIdx.x;
    for (int idx = tid; idx < K * 96; idx += 256) {
        int k = idx / 96, n = idx - k * 96;
        Wt[n * LDK + k] = (_Float16)W[idx];
    }
    if (ACT && tid < 96) {
        float inv_n = 1.0f / (float)N;
        float mean = bnsums[tid] * inv_n;
        float var = bnsums[96 + tid] * inv_n - mean * mean;
        float sc = gamma[tid] * rsqrtf(var + 1e-5f);
        ssl[tid] = sc;
        ssl[96 + tid] = beta[tid] - mean * sc;
    }
    if (STATS && tid < 192) sb[tid] = 0.0f;
    __syncthreads();

    const int wave = tid >> 6, lane = tid & 63;
    const int quad = lane >> 4, lm = lane & 15;
    const int rbase = bid * 64 + wave * 16;
    int arow = rbase + lm;
    arow = arow < N ? arow : N - 1;

    v8h afr[NK];
#pragma unroll
    for (int kc = 0; kc < NK; ++kc) {
        const int kk = kc * 32 + quad * 8;
        if constexpr (sizeof(TIN) == 4) {
            const float* p = (const float*)&in[(long long)arow * K + kk];
            float4 p0 = *(const float4*)p;
            float4 p1 = *(const float4*)(p + 4);
            if (ACT) {
                float4 sc0 = *(const float4*)&ssl[kk];
                float4 sc1 = *(const float4*)&ssl[kk + 4];
                float4 sh0 = *(const float4*)&ssl[96 + kk];
                float4 sh1 = *(const float4*)&ssl[96 + kk + 4];
                p0.x = fmaxf(fmaf(p0.x, sc0.x, sh0.x), 0.0f);
                p0.y = fmaxf(fmaf(p0.y, sc0.y, sh0.y), 0.0f);
                p0.z = fmaxf(fmaf(p0.z, sc0.z, sh0.z), 0.0f);
                p0.w = fmaxf(fmaf(p0.w, sc0.w, sh0.w), 0.0f);
                p1.x = fmaxf(fmaf(p1.x, sc1.x, sh1.x), 0.0f);
                p1.y = fmaxf(fmaf(p1.y, sc1.y, sh1.y), 0.0f);
                p1.z = fmaxf(fmaf(p1.z, sc1.z, sh1.z), 0.0f);
                p1.w = fmaxf(fmaf(p1.w, sc1.w, sh1.w), 0.0f);
            }
            v8h a;
            a[0] = (_Float16)p0.x; a[1] = (_Float16)p0.y;
            a[2] = (_Float16)p0.z; a[3] = (_Float16)p0.w;
            a[4] = (_Float16)p1.x; a[5] = (_Float16)p1.y;
            a[6] = (_Float16)p1.z; a[7] = (_Float16)p1.w;
            afr[kc] = a;
        } else {
            v8h hv = *(const v8h*)&in[(long long)arow * K + kk];
            if (ACT) {
#pragma unroll
                for (int j = 0; j < 8; ++j) {
                    float f = (float)hv[j];
                    f = fmaxf(fmaf(f, ssl[kk + j], ssl[96 + kk + j]), 0.0f);
                    hv[j] = (_Float16)f;
                }
            }
            afr[kc] = hv;
        }
    }

    v4f acc[6];
#pragma unroll
    for (int t = 0; t < 6; ++t) {
        v4f c = {0.0f, 0.0f, 0.0f, 0.0f};
#pragma unroll
        for (int kc = 0; kc < NK; ++kc) {
            v8h b = *(const v8h*)&Wt[(t * 16 + lm) * LDK + kc * 32 + quad * 8];
            c = __builtin_amdgcn_mfma_f32_16x16x32_f16(afr[kc], b, c, 0, 0, 0);
        }
        acc[t] = c;
    }

    float dr[4];
#pragma unroll
    for (int r = 0; r < 4; ++r) {
        int gr = rbase + quad * 4 + r;
        dr[r] = dsc ? dsc[gr < N ? gr : N - 1] : 1.0f;
    }

    float ls[6], lq[6];
#pragma unroll
    for (int t = 0; t < 6; ++t) { ls[t] = 0.0f; lq[t] = 0.0f; }
#pragma unroll
    for (int t = 0; t < 6; ++t) {
        float bv = BIAS ? bias[t * 16 + lm] : 0.0f;
#pragma unroll
        for (int r = 0; r < 4; ++r) {
            int gr = rbase + quad * 4 + r;
            if (gr < N) {
                float o = acc[t][r] + bv;
                hout[(long long)gr * 96 + t * 16 + lm] = (_Float16)(o * dr[r]);
                if (STATS) { ls[t] += o; lq[t] += o * o; }
            }
        }
    }
    if (STATS) {
#pragma unroll
        for (int t = 0; t < 6; ++t) {
            ls[t] += __shfl_xor(ls[t], 16);
            ls[t] += __shfl_xor(ls[t], 32);
            lq[t] += __shfl_xor(lq[t], 16);
            lq[t] += __shfl_xor(lq[t], 32);
        }
        if (quad == 0) {
#pragma unroll
            for (int t = 0; t < 6; ++t) {
                atomicAdd(&sb[t * 16 + lm], ls[t]);
                atomicAdd(&sb[96 + t * 16 + lm], lq[t]);
            }
        }
        __syncthreads();
        if (tid < 192) atomicAdd(&osums[tid], sb[tid]);
    }
}

template <int K, bool ACT, bool BIAS, bool STATS, typename TIN>
__global__ __launch_bounds__(256) void gemm96m(const TIN* __restrict__ in,
                                               const float* __restrict__ W,
                                               const float* __restrict__ bias,
                                               const float* __restrict__ bnsums,
                                               const float* __restrict__ gamma,
                                               const float* __restrict__ beta,
                                               const float* __restrict__ dsc,
                                               _Float16* __restrict__ hout,
                                               float* __restrict__ osums, int N) {
    gemm96_body<K, ACT, BIAS, STATS, TIN>(blockIdx.x, in, W, bias, bnsums,
                                          gamma, beta, dsc, hout, osums, N);
}

// layer-1 GEMM overlapped with the edge-count pass (independent inputs/outputs;
// GEMM is MFMA+stream-bound, count is atomic-bound -> complementary pipes).
// blocks [0,gG): GEMM.  blocks [gG, gG+gC): grid-stride in-degree count.
__global__ __launch_bounds__(256) void gemm1_count(const float* __restrict__ x,
                                                   const float* __restrict__ W1,
                                                   _Float16* __restrict__ hout,
                                                   const int* __restrict__ dst,
                                                   int* __restrict__ cnt,
                                                   unsigned short* __restrict__ eoff,
                                                   int gG, int N, int E) {
    if ((int)blockIdx.x < gG) {
        gemm96_body<128, false, false, false, float>(
            blockIdx.x, x, W1, nullptr, nullptr, nullptr, nullptr, nullptr,
            hout, nullptr, N);
    } else {
        int g = (blockIdx.x - gG) * 256 + threadIdx.x;
        int stride = (gridDim.x - gG) * 256;
        for (int i = g; i < E; i += stride)
            eoff[i] = (unsigned short)atomicAdd(&cnt[dst[i]], 1);
    }
}

// ---------------- MFMA final GEMM: l2norm(act(in) @ Wp2[96,64] + bp2) -------

__global__ __launch_bounds__(256) void gemm_finalm(const _Float16* __restrict__ in,
                                                   const float* __restrict__ W,
                                                   const float* __restrict__ bias,
                                                   const float* __restrict__ bnsums,
                                                   const float* __restrict__ gamma,
                                                   const float* __restrict__ beta,
                                                   float* __restrict__ out, int N) {
    constexpr int K = 96, NK = 3, LDK = K + 8;
    __shared__ __align__(16) _Float16 Wt[64 * LDK];
    __shared__ __align__(16) float ssl[192];
    const int tid = threadIdx.x;
    for (int idx = tid; idx < K * 64; idx += 256) {
        int k = idx / 64, n = idx - k * 64;
        Wt[n * LDK + k] = (_Float16)W[idx];
    }
    if (tid < 96) {
        float inv_n = 1.0f / (float)N;
        float mean = bnsums[tid] * inv_n;
        float var = bnsums[96 + tid] * inv_n - mean * mean;
        float sc = gamma[tid] * rsqrtf(var + 1e-5f);
        ssl[tid] = sc;
        ssl[96 + tid] = beta[tid] - mean * sc;
    }
    __syncthreads();

    const int wave = tid >> 6, lane = tid & 63;
    const int quad = lane >> 4, lm = lane & 15;
    const int rbase = blockIdx.x * 64 + wave * 16;
    int arow = rbase + lm;
    arow = arow < N ? arow : N - 1;

    v8h afr[NK];
#pragma unroll
    for (int kc = 0; kc < NK; ++kc) {
        const int kk = kc * 32 + quad * 8;
        v8h hv = *(const v8h*)&in[(long long)arow * K + kk];
#pragma unroll
        for (int j = 0; j < 8; ++j) {
            float f = (float)hv[j];
            f = fmaxf(fmaf(f, ssl[kk + j], ssl[96 + kk + j]), 0.0f);
            hv[j] = (_Float16)f;
        }
        afr[kc] = hv;
    }

    v4f acc[4];
#pragma unroll
    for (int t = 0; t < 4; ++t) {
        v4f c = {0.0f, 0.0f, 0.0f, 0.0f};
#pragma unroll
        for (int kc = 0; kc < NK; ++kc) {
            v8h b = *(const v8h*)&Wt[(t * 16 + lm) * LDK + kc * 32 + quad * 8];
            c = __builtin_amdgcn_mfma_f32_16x16x32_f16(afr[kc], b, c, 0, 0, 0);
        }
        float bv = bias[t * 16 + lm];
        c[0] += bv; c[1] += bv; c[2] += bv; c[3] += bv;
        acc[t] = c;
    }

    float sq[4];
#pragma unroll
    for (int r = 0; r < 4; ++r) {
        float s = acc[0][r] * acc[0][r] + acc[1][r] * acc[1][r] +
                  acc[2][r] * acc[2][r] + acc[3][r] * acc[3][r];
#pragma unroll
        for (int m = 1; m < 16; m <<= 1) s += __shfl_xor(s, m, 64);
        sq[r] = 1.0f / fmaxf(sqrtf(s), 1e-12f);
    }
#pragma unroll
    for (int r = 0; r < 4; ++r) {
        int gr = rbase + quad * 4 + r;
        if (gr < N) {
#pragma unroll
            for (int t = 0; t < 4; ++t)
                out[(long long)gr * 64 + t * 16 + lm] = acc[t][r] * sq[r];
        }
    }
}

// ---------------- CSR pull aggregation (fp16 gather, 2-B edge index) ---------
// PRESC=true : rows pre-scaled by dis[src] -> out = b + dn*(h[n] + sum h[s])
// PRESC=false: raw rows -> acc = dn*h[n] + sum dis[s]*h[s]; out = b + dn*acc
// Output fp16 (accumulate fp32, one rounding on store). 12 threads/node,
// 8 cols each, edge loop unrolled x8/x4 (R9-proven batching).

__device__ __forceinline__ void acc_row(float* acc, const __half2* h) {
#pragma unroll
    for (int k = 0; k < 4; ++k) {
        float2 f = __half22float2(h[k]);
        acc[2 * k + 0] += f.x;
        acc[2 * k + 1] += f.y;
    }
}

__device__ __forceinline__ void acc_roww(float* acc, const __half2* h, float w) {
#pragma unroll
    for (int k = 0; k < 4; ++k) {
        float2 f = __half22float2(h[k]);
        acc[2 * k + 0] = fmaf(f.x, w, acc[2 * k + 0]);
        acc[2 * k + 1] = fmaf(f.y, w, acc[2 * k + 1]);
    }
}

template <bool PRESC>
__global__ __launch_bounds__(256) void agg96h(const __half* __restrict__ hxw,
                                              const int* __restrict__ rowptr,
                                              const unsigned short* __restrict__ csrc,
                                              const float* __restrict__ dis,
                                              const float* __restrict__ bias,
                                              _Float16* __restrict__ outh, int N) {
    int idx = blockIdx.x * 256 + threadIdx.x;
    if (idx >= N * 12) return;
    int n = idx / 12, c8 = idx % 12;
    int ch = c8 * 8;
    float dn = dis[n];
    float acc[8];
    {
        float sw = PRESC ? 1.0f : dn;
        float4 g = *(const float4*)&hxw[(long long)n * 96 + ch];
        const __half2* hs = (const __half2*)&g;
#pragma unroll
        for (int k = 0; k < 4; ++k) {
            float2 f = __half22float2(hs[k]);
            acc[2 * k + 0] = f.x * sw;
            acc[2 * k + 1] = f.y * sw;
        }
    }
    int e = rowptr[n], e1 = rowptr[n + 1];
    for (; e + 7 < e1; e += 8) {
        int s[8];
        float4 g[8];
        float w[8];
#pragma unroll
        for (int j = 0; j < 8; ++j) s[j] = csrc[e + j];
        if (!PRESC) {
#pragma unroll
            for (int j = 0; j < 8; ++j) w[j] = dis[s[j]];
        }
#pragma unroll
        for (int j = 0; j < 8; ++j)
            g[j] = *(const float4*)&hxw[(long long)s[j] * 96 + ch];
#pragma unroll
        for (int j = 0; j < 8; ++j) {
            if (PRESC) acc_row(acc, (const __half2*)&g[j]);
            else       acc_roww(acc, (const __half2*)&g[j], w[j]);
        }
    }
    for (; e + 3 < e1; e += 4) {
        int s[4];
        float4 g[4];
        float w[4];
#pragma unroll
        for (int j = 0; j < 4; ++j) s[j] = csrc[e + j];
        if (!PRESC) {
#pragma unroll
            for (int j = 0; j < 4; ++j) w[j] = dis[s[j]];
        }
#pragma unroll
        for (int j = 0; j < 4; ++j)
            g[j] = *(const float4*)&hxw[(long long)s[j] * 96 + ch];
#pragma unroll
        for (int j = 0; j < 4; ++j) {
            if (PRESC) acc_row(acc, (const __half2*)&g[j]);
            else       acc_roww(acc, (const __half2*)&g[j], w[j]);
        }
    }
    for (; e < e1; ++e) {
        int s0 = csrc[e];
        float4 g0 = *(const float4*)&hxw[(long long)s0 * 96 + ch];
        if (PRESC) acc_row(acc, (const __half2*)&g0);
        else       acc_roww(acc, (const __half2*)&g0, dis[s0]);
    }
    v8h o;
#pragma unroll
    for (int j = 0; j < 8; ++j)
        o[j] = (_Float16)fmaf(acc[j], dn, bias[ch + j]);
    *(v8h*)&outh[(long long)n * 96 + ch] = o;
}

// ---------------- BN stats over fp16 buffer (coalesced grid-stride) ----------
// grid must be a multiple of 3 so stride = grid*256 is a multiple of 12
// (fixed c8 = g%12 requires i%12 invariant across the stride loop).

__global__ __launch_bounds__(256) void bn_stats96h(const __half* __restrict__ h,
                                                   float* __restrict__ sums, int N) {
    __shared__ float sb[192];
    const int tid = threadIdx.x;
    if (tid < 192) sb[tid] = 0.0f;
    __syncthreads();
    int g = blockIdx.x * 256 + tid;
    int total = N * 12, stride = gridDim.x * 256;
    int c8 = g % 12;
    float s[8] = {0, 0, 0, 0, 0, 0, 0, 0};
    float q[8] = {0, 0, 0, 0, 0, 0, 0, 0};
    for (int i = g; i < total; i += stride) {
        int n = i / 12;
        float4 raw = *(const float4*)&h[n * 96 + 8 * c8];
        const __half2* hp = (const __half2*)&raw;
#pragma unroll
        for (int k = 0; k < 4; ++k) {
            float2 f = __half22float2(hp[k]);
            s[2 * k + 0] += f.x;
            s[2 * k + 1] += f.y;
            q[2 * k + 0] += f.x * f.x;
            q[2 * k + 1] += f.y * f.y;
        }
    }
#pragma unroll
    for (int j = 0; j < 8; ++j) {
        atomicAdd(&sb[8 * c8 + j], s[j]);
        atomicAdd(&sb[96 + 8 * c8 + j], q[j]);
    }
    __syncthreads();
    if (tid < 192) atomicAdd(&sums[tid], sb[tid]);
}

// ---------------- launch ----------------

extern "C" void kernel_launch(void* const* d_in, const int* in_sizes, int n_in,
                              void* d_out, int out_size, void* d_ws, size_t ws_size,
                              hipStream_t stream) {
    const float* x   = (const float*)d_in[0];
    const int*   ei  = (const int*)d_in[1];
    const float* W1  = (const float*)d_in[2];
    const float* b1  = (const float*)d_in[3];
    const float* g1  = (const float*)d_in[4];
    const float* be1 = (const float*)d_in[5];
    const float* W2  = (const float*)d_in[6];
    const float* b2  = (const float*)d_in[7];
    const float* g2  = (const float*)d_in[8];
    const float* be2 = (const float*)d_in[9];
    const float* Wp1 = (const float*)d_in[10];
    const float* bp1 = (const float*)d_in[11];
    const float* gp  = (const float*)d_in[12];
    const float* bep = (const float*)d_in[13];
    const float* Wp2 = (const float*)d_in[14];
    const float* bp2 = (const float*)d_in[15];

    const int N = in_sizes[0] / 128;   // 50000 (< 2^16 -> uint16 indices ok)
    const int E = in_sizes[1] / 2;     // 800000
    const int* src = ei;
    const int* dst = ei + E;

    // workspace layout (cnt and sums adjacent -> one memsetAsync zeroes both)
    char* w = (char*)d_ws;
    auto alloc = [&](size_t bytes) { char* p = w; w += (bytes + 15) & ~size_t(15); return p; };
    int*            cnt    = (int*)alloc((size_t)N * 4);
    float*          sums   = (float*)alloc(576 * 4);
    int*            rowptr = (int*)alloc((size_t)(N + 1) * 4);
    int*            bsum   = (int*)alloc(64 * 4);
    float*          dis    = (float*)alloc((size_t)N * 4);
    unsigned short* eoff   = (unsigned short*)alloc((size_t)E * 2);
    unsigned short* csrc   = (unsigned short*)alloc((size_t)E * 2);
    _Float16*       buf2h  = (_Float16*)alloc((size_t)N * 96 * 2);
    _Float16*       hbuf   = (_Float16*)alloc((size_t)N * 96 * 2);
    float* sums1 = sums, *sums2 = sums + 192, *sums3 = sums + 384;

    float* out = (float*)d_out;

    const int gE  = cdiv(E, BLK);                  // 3125 fill blocks
    const int gG  = cdiv(N, 64);                   // 782 gemm blocks
    const int gC  = 1024;                          // count blocks (grid-stride)
    const int gA  = cdiv((long long)N * 12, BLK);  // 2344 agg blocks
    const int nb  = cdiv(N, 1024);                 // scan chunks (49)

    // zero cnt + BN sums (adjacent allocations -> single contiguous memset)
    size_t zlen = (size_t)((char*)sums - (char*)cnt) + 576 * 4;
    hipMemsetAsync(cnt, 0, zlen, stream);

    // D1: layer-1 GEMM (fp16 shadow, unscaled) overlapped with edge count
    gemm1_count<<<gG + gC, 256, 0, stream>>>(x, W1, hbuf, dst, cnt, eoff, gG, N, E);
    // D2-D4: CSR build (chunk scan+dis -> apply offsets -> atomic-free fill)
    scan1_dis<<<nb, 256, 0, stream>>>(cnt, rowptr, bsum, dis, N);
    scan23<<<cdiv(N, 256), 256, 0, stream>>>(rowptr, bsum, nb, N, E);
    csr_fill<<<gE, BLK, 0, stream>>>(src, dst, eoff, rowptr, csrc, E);

    // D5-D6: layer-1 agg (dis gathered per edge) -> fp16 buf2h; BN1 stats
    agg96h<false><<<gA, 256, 0, stream>>>((const __half*)hbuf, rowptr, csrc, dis,
                                          b1, buf2h, N);
    bn_stats96h<<<510, 256, 0, stream>>>((const __half*)buf2h, sums1, N);

    // D7-D9: layer 2 (BN1 fused, fp16 in; dis-prescaled fp16 out) + agg + BN2
    gemm96m<96, true, false, false, _Float16><<<gG, 256, 0, stream>>>(
        buf2h, W2, nullptr, sums1, g1, be1, dis, hbuf, nullptr, N);
    agg96h<true><<<gA, 256, 0, stream>>>((const __half*)hbuf, rowptr, csrc, dis,
                                         b2, buf2h, N);
    bn_stats96h<<<510, 256, 0, stream>>>((const __half*)buf2h, sums2, N);

    // D10: projector linear 1 (BN2 fused; fp16 out into hbuf; BN3 stats fused)
    gemm96m<96, true, true, true, _Float16><<<gG, 256, 0, stream>>>(
        buf2h, Wp1, bp1, sums2, g2, be2, nullptr, hbuf, sums3, N);

    // D11: projector linear 2 (BN3 fused + bias + L2 normalize), fp16 in
    gemm_finalm<<<gG, 256, 0, stream>>>(hbuf, Wp2, bp2, sums3, gp, bep, out, N);
}